// Round 2
// baseline (38335.614 us; speedup 1.0000x reference)
//
#include <hip/hip_runtime.h>

// ---------------------------------------------------------------------------
// SimpleGPT forward on MI355X. Round 2: batch-chunked to fit ws_size.
//   Crash theory from R1: ws layout assumed 660MB scratch; never checked
//   ws_size -> OOB writes -> GPU fault/abort. Now the forward runs in batch
//   chunks of chunkB sequences (whole net per chunk); per-chunk scratch is
//   7 units (U = chunkB*60*384*2 B): x fp32 (2U) | h bf16 (1U) | region (4U)
//   holding q|k|v (ao aliases q; MLP hidden f aliases the whole region).
//   chunkB picked at launch time: largest in {2048..16} with 7U <= ws_size.
// ---------------------------------------------------------------------------

#define B_  2048
#define T_  60
#define C_  384
#define H_  6
#define HS_ 64
#define L_  6
#define FF_ 1536
#define V_  65

typedef unsigned int  u32;
typedef unsigned short u16;

__device__ __forceinline__ float bf2f(u32 u) {
  return __uint_as_float(u << 16);
}
__device__ __forceinline__ u16 f2bf(float f) {
  u32 u = __float_as_uint(f);
  u = u + 0x7FFFu + ((u >> 16) & 1u);   // RNE; inputs are finite
  return (u16)(u >> 16);
}

// ---------------------------------------------------------------- embedding
// grid covers BTc*C/4 float4 elements exactly; ctx is chunk-local pointer.
__global__ __launch_bounds__(256) void embed_k(const int* __restrict__ ctx,
    const float* __restrict__ tok, const float* __restrict__ pos,
    float* __restrict__ x)
{
  int idx = blockIdx.x * 256 + threadIdx.x;
  int row = idx / (C_ / 4);
  int c   = (idx % (C_ / 4)) * 4;
  int t   = row % T_;               // chunk starts at a sequence boundary
  int tk  = ctx[row];
  float4 a = *(const float4*)(tok + (long)tk * C_ + c);
  float4 p = *(const float4*)(pos + (long)t  * C_ + c);
  float4 o = make_float4(a.x + p.x, a.y + p.y, a.z + p.z, a.w + p.w);
  *(float4*)(x + (long)idx * 4) = o;
}

// ---------------------------------------------------------------- layernorm
// one wave per token; lane handles 6 consecutive channels (64*6 = 384)
__global__ __launch_bounds__(256) void ln_k(const float* __restrict__ x,
    const float* __restrict__ g, const float* __restrict__ b,
    u16* __restrict__ h)
{
  int lane = threadIdx.x & 63;
  int wv   = threadIdx.x >> 6;
  long row = (long)blockIdx.x * 4 + wv;
  const float* xr = x + row * C_;
  int c0 = lane * 6;
  float v0[6];
  #pragma unroll
  for (int i = 0; i < 6; i++) v0[i] = xr[c0 + i];
  float s = 0.f, sq = 0.f;
  #pragma unroll
  for (int i = 0; i < 6; i++) { s += v0[i]; sq += v0[i] * v0[i]; }
  #pragma unroll
  for (int off = 32; off > 0; off >>= 1) {
    s  += __shfl_xor(s,  off, 64);
    sq += __shfl_xor(sq, off, 64);
  }
  float mu  = s * (1.f / C_);
  float var = sq * (1.f / C_) - mu * mu;
  float rs  = rsqrtf(var + 1e-5f);
  u16* hr = h + row * C_;
  #pragma unroll
  for (int i = 0; i < 6; i++) {
    float hv = (v0[i] - mu) * rs * g[c0 + i] + b[c0 + i];
    hr[c0 + i] = f2bf(hv);
  }
}

// ---------------------------------------------------------------- GEMM
// out[M,N] = act(A[M,K](bf16) @ W[K,N](fp32) + bias) [+ resid]
// W addressing: W[k*wK + nt*wTile + dn]  (covers row-major and the
// head-blocked [H,C,HS] qkv layout: wTile=C*HS, wK=HS)
// tile 64x64, K-step 16, 256 threads, 4x4 micro-tile per thread.
template<int RELU, int RES, int OBF>
__global__ __launch_bounds__(256) void gemm_k(const u16* __restrict__ A,
    const float* __restrict__ W, long wTile, int wK,
    const float* __restrict__ bias, const float* __restrict__ resid,
    void* __restrict__ outp, int N, int K)
{
  __shared__ float As[16][68];   // [k][row], padded
  __shared__ float Ws[16][68];   // [k][col], padded
  int tid   = threadIdx.x;
  long mBase = (long)blockIdx.x * 64;
  int nt    = blockIdx.y;
  int nBase = nt * 64;
  int r0 = (tid >> 4) << 2;
  int c0 = (tid & 15) << 2;
  int arow = tid >> 2;           // 0..63
  int akg  = (tid & 3) << 2;     // 0,4,8,12
  int wkk  = tid >> 4;           // 0..15
  int wng  = (tid & 15) << 2;    // 0..60
  bool fullN = (nBase + 64 <= N);
  float acc[4][4] = {};

  for (int k0 = 0; k0 < K; k0 += 16) {
    uint2 ar = *(const uint2*)(A + (mBase + arow) * K + k0 + akg);
    As[akg + 0][arow] = bf2f(ar.x & 0xffffu);
    As[akg + 1][arow] = bf2f(ar.x >> 16);
    As[akg + 2][arow] = bf2f(ar.y & 0xffffu);
    As[akg + 3][arow] = bf2f(ar.y >> 16);
    const float* wp = W + (long)(k0 + wkk) * wK + (long)nt * wTile;
    if (fullN) {
      float4 w4 = *(const float4*)(wp + wng);
      *(float4*)&Ws[wkk][wng] = w4;
    } else {
      #pragma unroll
      for (int i2 = 0; i2 < 4; i2++) {
        int n = nBase + wng + i2;
        Ws[wkk][wng + i2] = (n < N) ? wp[wng + i2] : 0.f;
      }
    }
    __syncthreads();
    #pragma unroll
    for (int kk = 0; kk < 16; kk++) {
      float4 a4 = *(const float4*)&As[kk][r0];
      float4 b4 = *(const float4*)&Ws[kk][c0];
      float av[4] = {a4.x, a4.y, a4.z, a4.w};
      float bv[4] = {b4.x, b4.y, b4.z, b4.w};
      #pragma unroll
      for (int i2 = 0; i2 < 4; i2++)
        #pragma unroll
        for (int j2 = 0; j2 < 4; j2++)
          acc[i2][j2] = fmaf(av[i2], bv[j2], acc[i2][j2]);
    }
    __syncthreads();
  }

  #pragma unroll
  for (int i2 = 0; i2 < 4; i2++) {
    long row = mBase + r0 + i2;
    #pragma unroll
    for (int j2 = 0; j2 < 4; j2++) {
      int n = nBase + c0 + j2;
      if (n < N) {
        float vv = acc[i2][j2];
        if (bias)  vv += bias[n];
        if (RELU)  vv = fmaxf(vv, 0.f);
        if (RES)   vv += resid[row * N + n];
        if (OBF) ((u16*)outp)[row * N + n] = f2bf(vv);
        else     ((float*)outp)[row * N + n] = vv;
      }
    }
  }
}

// ---------------------------------------------------------------- attention
// one block per (b, head). q,k,v bf16 [BTc, C] slices -> LDS fp32; causal
// softmax; PV; writes concat-head output. ao may alias q: all q reads finish
// (first loop + barrier) before any ao write (last loop), per block; slices
// are disjoint across blocks.
__global__ __launch_bounds__(256) void attn_k(const u16* __restrict__ q,
    const u16* __restrict__ k, const u16* __restrict__ v,
    u16* __restrict__ ao)
{
  __shared__ float qs[T_][64];
  __shared__ float kT[64][64];
  __shared__ float vs[T_][64];
  __shared__ float ps[T_][64];
  int tid = threadIdx.x;
  int bb = blockIdx.x / H_;
  int hh = blockIdx.x % H_;
  long base = ((long)bb * T_) * C_ + hh * HS_;

  for (int i = tid; i < T_ * 8; i += 256) {
    int t = i >> 3, d0 = (i & 7) << 3;
    long off = base + (long)t * C_ + d0;
    uint4 r; float f[8];
    r = *(const uint4*)(q + off);
    f[0]=bf2f(r.x&0xffffu); f[1]=bf2f(r.x>>16); f[2]=bf2f(r.y&0xffffu); f[3]=bf2f(r.y>>16);
    f[4]=bf2f(r.z&0xffffu); f[5]=bf2f(r.z>>16); f[6]=bf2f(r.w&0xffffu); f[7]=bf2f(r.w>>16);
    #pragma unroll
    for (int m = 0; m < 8; m++) qs[t][d0 + m] = f[m];
    r = *(const uint4*)(v + off);
    f[0]=bf2f(r.x&0xffffu); f[1]=bf2f(r.x>>16); f[2]=bf2f(r.y&0xffffu); f[3]=bf2f(r.y>>16);
    f[4]=bf2f(r.z&0xffffu); f[5]=bf2f(r.z>>16); f[6]=bf2f(r.w&0xffffu); f[7]=bf2f(r.w>>16);
    #pragma unroll
    for (int m = 0; m < 8; m++) vs[t][d0 + m] = f[m];
    r = *(const uint4*)(k + off);
    f[0]=bf2f(r.x&0xffffu); f[1]=bf2f(r.x>>16); f[2]=bf2f(r.y&0xffffu); f[3]=bf2f(r.y>>16);
    f[4]=bf2f(r.z&0xffffu); f[5]=bf2f(r.z>>16); f[6]=bf2f(r.w&0xffffu); f[7]=bf2f(r.w>>16);
    #pragma unroll
    for (int m = 0; m < 8; m++) kT[d0 + m][t] = f[m];
  }
  __syncthreads();

  for (int idx = tid; idx < T_ * T_; idx += 256) {
    int i = idx / T_, j = idx - i * T_;
    if (j <= i) {
      float acc = 0.f;
      #pragma unroll 16
      for (int d = 0; d < 64; d++) acc = fmaf(qs[i][d], kT[d][j], acc);
      ps[i][j] = acc * 0.125f;                    // HS^-0.5
    }
  }
  __syncthreads();

  int lane = tid & 63, wv = tid >> 6;
  for (int i = wv; i < T_; i += 4) {
    float val = (lane <= i) ? ps[i][lane] : -1e30f;
    float m = val;
    #pragma unroll
    for (int off = 32; off > 0; off >>= 1) m = fmaxf(m, __shfl_xor(m, off, 64));
    float e = (lane <= i) ? __expf(val - m) : 0.f;
    float s2 = e;
    #pragma unroll
    for (int off = 32; off > 0; off >>= 1) s2 += __shfl_xor(s2, off, 64);
    ps[i][lane] = e / s2;                         // rows j>i get exactly 0
  }
  __syncthreads();

  for (int g2 = tid; g2 < T_ * 16; g2 += 256) {
    int t = g2 >> 4, d0 = (g2 & 15) << 2;
    float a0 = 0, a1 = 0, a2 = 0, a3 = 0;
    for (int j = 0; j < T_; j++) {
      float p = ps[t][j];
      float4 v4 = *(const float4*)&vs[j][d0];
      a0 = fmaf(p, v4.x, a0); a1 = fmaf(p, v4.y, a1);
      a2 = fmaf(p, v4.z, a2); a3 = fmaf(p, v4.w, a3);
    }
    long off = base + (long)t * C_ + d0;
    uint2 o2;
    o2.x = (u32)f2bf(a0) | ((u32)f2bf(a1) << 16);
    o2.y = (u32)f2bf(a2) | ((u32)f2bf(a3) << 16);
    *(uint2*)(ao + off) = o2;
  }
}

// ---------------------------------------------------------------- launch
extern "C" void kernel_launch(void* const* d_in, const int* in_sizes, int n_in,
                              void* d_out, int out_size, void* d_ws, size_t ws_size,
                              hipStream_t stream)
{
  const int*   ctx  = (const int*)  d_in[0];
  const float* tok  = (const float*)d_in[1];
  const float* pos  = (const float*)d_in[2];
  const float* wq   = (const float*)d_in[3];
  const float* wk   = (const float*)d_in[4];
  const float* wv   = (const float*)d_in[5];
  const float* wo   = (const float*)d_in[6];
  const float* bo   = (const float*)d_in[7];
  const float* ln1g = (const float*)d_in[8];
  const float* ln1b = (const float*)d_in[9];
  const float* ln2g = (const float*)d_in[10];
  const float* ln2b = (const float*)d_in[11];
  const float* w1   = (const float*)d_in[12];
  const float* b1   = (const float*)d_in[13];
  const float* w2   = (const float*)d_in[14];
  const float* b2   = (const float*)d_in[15];
  const float* lnfg = (const float*)d_in[16];
  const float* lnfb = (const float*)d_in[17];
  const float* lmw  = (const float*)d_in[18];
  const float* lmb  = (const float*)d_in[19];
  float* out = (float*)d_out;

  // pick largest chunk (in sequences) whose scratch fits ws_size.
  // scratch = 7 units; U = chunkB*T*C*2 bytes.
  int chunkB = 16;
  {
    const int cand[] = {2048, 1024, 512, 256, 128, 64, 32, 16};
    for (int i = 0; i < 8; i++) {
      size_t U = (size_t)cand[i] * T_ * C_ * 2;
      if (7 * U <= ws_size) { chunkB = cand[i]; break; }
    }
  }
  const long BTc = (long)chunkB * T_;
  char* wsb = (char*)d_ws;
  const size_t U = (size_t)BTc * C_ * 2;
  float* x   = (float*)wsb;              // 2U
  u16*   h   = (u16*)(wsb + 2 * U);      // 1U
  char*  reg = wsb + 3 * U;              // 4U
  u16* qb = (u16*)reg;
  u16* kb = (u16*)(reg + U);
  u16* vb = (u16*)(reg + 2 * U);
  u16* ab = qb;                          // alias: safe (see attn_k comment)
  u16* fb = (u16*)reg;                   // alias: k/v dead before MLP

  const long wqL = (long)H_ * C_ * HS_;
  dim3 blk(256);
  dim3 gEmb((u32)(BTc * C_ / 4 / 256));
  dim3 gLN((u32)(BTc / 4));
  dim3 g6((u32)(BTc / 64), C_ / 64);
  dim3 g24((u32)(BTc / 64), FF_ / 64);
  dim3 gHd((u32)(BTc / 64), (V_ + 63) / 64);
  dim3 gAt((u32)(chunkB * H_));

  for (int c0 = 0; c0 < B_; c0 += chunkB) {
    const long tok0 = (long)c0 * T_;
    const int* ctxc = ctx + tok0;
    float* outc = out + tok0 * V_;

    embed_k<<<gEmb, blk, 0, stream>>>(ctxc, tok, pos, x);

    for (int l = 0; l < L_; l++) {
      ln_k<<<gLN, blk, 0, stream>>>(x, ln1g + l * C_, ln1b + l * C_, h);
      gemm_k<0,0,1><<<g6, blk, 0, stream>>>(h, wq + (long)l * wqL,
          (long)C_ * HS_, HS_, nullptr, nullptr, qb, C_, C_);
      gemm_k<0,0,1><<<g6, blk, 0, stream>>>(h, wk + (long)l * wqL,
          (long)C_ * HS_, HS_, nullptr, nullptr, kb, C_, C_);
      gemm_k<0,0,1><<<g6, blk, 0, stream>>>(h, wv + (long)l * wqL,
          (long)C_ * HS_, HS_, nullptr, nullptr, vb, C_, C_);
      attn_k<<<gAt, blk, 0, stream>>>(qb, kb, vb, ab);
      gemm_k<0,1,0><<<g6, blk, 0, stream>>>(ab, wo + (long)l * C_ * C_,
          64L, C_, bo + l * C_, x, x, C_, C_);
      ln_k<<<gLN, blk, 0, stream>>>(x, ln2g + l * C_, ln2b + l * C_, h);
      gemm_k<1,0,1><<<g24, blk, 0, stream>>>(h, w1 + (long)l * C_ * FF_,
          64L, FF_, b1 + l * FF_, nullptr, fb, FF_, C_);
      gemm_k<0,1,0><<<g6, blk, 0, stream>>>(fb, w2 + (long)l * FF_ * C_,
          64L, C_, b2 + l * C_, x, x, C_, FF_);
    }

    ln_k<<<gLN, blk, 0, stream>>>(x, lnfg, lnfb, h);
    gemm_k<0,0,0><<<gHd, blk, 0, stream>>>(h, lmw, 64L, V_, lmb, nullptr,
        outc, V_, C_);
  }
}

// Round 3
// 13298.460 us; speedup vs baseline: 2.8827x; 2.8827x over previous
//
#include <hip/hip_runtime.h>

// ---------------------------------------------------------------------------
// SimpleGPT forward on MI355X. Round 3: bf16 MFMA GEMMs.
//   - weights transposed+converted to bf16 once per call into ws front
//     (21.3 MB): Wt[n][k] layout so B staging = contiguous uint4, and the
//     B fragment load is identical to A's (B^T trick from the guide ladder).
//   - gemm_mfma: BM=128 BN=64 BK=32, 4 waves, per wave 2x4 tiles of
//     v_mfma_f32_16x16x32_bf16; LDS [kseg][row][8] so frag reads are
//     ds_read_b128 with 2-way (free) bank aliasing.
//   - grid = (Ntiles, Mtiles): N fastest -> A fetched once per m-row.
//   - batch-chunked as R2; scratch = weights(21.3MB) + 7U.
// ---------------------------------------------------------------------------

#define B_  2048
#define T_  60
#define C_  384
#define H_  6
#define HS_ 64
#define L_  6
#define FF_ 1536
#define V_  65

typedef unsigned int  u32;
typedef unsigned short u16;
typedef short bf16x8 __attribute__((ext_vector_type(8)));
typedef float f32x4  __attribute__((ext_vector_type(4)));

__device__ __forceinline__ float bf2f(u32 u) {
  return __uint_as_float(u << 16);
}
__device__ __forceinline__ u16 f2bf(float f) {
  u32 u = __float_as_uint(f);
  u = u + 0x7FFFu + ((u >> 16) & 1u);   // RNE; inputs are finite
  return (u16)(u >> 16);
}

// ------------------------------------------------ weight transpose+convert
// src fp32 [K][N] (numMat matrices) -> dst bf16 [N][K]
__global__ void tconv_k(const float* __restrict__ src, u16* __restrict__ dst,
                        int K, int N, long srcStride, long dstStride)
{
  __shared__ float t[32][33];
  long mat = blockIdx.z;
  const float* s = src + mat * srcStride;
  u16* d = dst + mat * dstStride;
  int n0 = blockIdx.x * 32, k0 = blockIdx.y * 32;
  for (int yy = threadIdx.y; yy < 32; yy += 8) {
    int k = k0 + yy, n = n0 + threadIdx.x;
    t[yy][threadIdx.x] = (k < K && n < N) ? s[(long)k * N + n] : 0.f;
  }
  __syncthreads();
  for (int yy = threadIdx.y; yy < 32; yy += 8) {
    int n = n0 + yy, k = k0 + threadIdx.x;
    if (n < N && k < K) d[(long)n * K + k] = f2bf(t[threadIdx.x][yy]);
  }
}

// ---------------------------------------------------------------- embedding
__global__ __launch_bounds__(256) void embed_k(const int* __restrict__ ctx,
    const float* __restrict__ tok, const float* __restrict__ pos,
    float* __restrict__ x)
{
  int idx = blockIdx.x * 256 + threadIdx.x;
  int row = idx / (C_ / 4);
  int c   = (idx % (C_ / 4)) * 4;
  int t   = row % T_;
  int tk  = ctx[row];
  float4 a = *(const float4*)(tok + (long)tk * C_ + c);
  float4 p = *(const float4*)(pos + (long)t  * C_ + c);
  float4 o = make_float4(a.x + p.x, a.y + p.y, a.z + p.z, a.w + p.w);
  *(float4*)(x + (long)idx * 4) = o;
}

// ---------------------------------------------------------------- layernorm
__global__ __launch_bounds__(256) void ln_k(const float* __restrict__ x,
    const float* __restrict__ g, const float* __restrict__ b,
    u16* __restrict__ h)
{
  int lane = threadIdx.x & 63;
  int wv   = threadIdx.x >> 6;
  long row = (long)blockIdx.x * 4 + wv;
  const float* xr = x + row * C_;
  int c0 = lane * 6;
  float v0[6];
  #pragma unroll
  for (int i = 0; i < 6; i++) v0[i] = xr[c0 + i];
  float s = 0.f, sq = 0.f;
  #pragma unroll
  for (int i = 0; i < 6; i++) { s += v0[i]; sq += v0[i] * v0[i]; }
  #pragma unroll
  for (int off = 32; off > 0; off >>= 1) {
    s  += __shfl_xor(s,  off, 64);
    sq += __shfl_xor(sq, off, 64);
  }
  float mu  = s * (1.f / C_);
  float var = sq * (1.f / C_) - mu * mu;
  float rs  = rsqrtf(var + 1e-5f);
  u16* hr = h + row * C_;
  #pragma unroll
  for (int i = 0; i < 6; i++) {
    float hv = (v0[i] - mu) * rs * g[c0 + i] + b[c0 + i];
    hr[c0 + i] = f2bf(hv);
  }
}

// ------------------------------------------------------------- MFMA GEMM
// out[M,N] = act(A[M,K](bf16) @ Wt^T + bias) [+ resid]
// Wt is bf16 [N][K] (transposed); tile nt covers cols nt*64..+63 at
// Wt + nt*64*K. BM=128 BN=64 BK=32; 256 thr (4 waves); wave w handles rows
// w*32..+31 as 2 row-tiles x 4 col-tiles of 16x16x32 MFMA.
template<int RELU, int RES, int OBF>
__global__ __launch_bounds__(256) void gemm_mfma(const u16* __restrict__ A,
    const u16* __restrict__ Wt, const float* __restrict__ bias,
    const float* __restrict__ resid, void* __restrict__ outp, int N, int K)
{
  __shared__ __align__(16) u16 As[4][128][8];   // [kseg][row][kj]  8 KB
  __shared__ __align__(16) u16 Bs[4][64][8];    // [kseg][col][kj]  4 KB
  int tid  = threadIdx.x;
  int nt   = blockIdx.x;
  int nBase = nt * 64;
  long mBase = (long)blockIdx.y * 128;
  int lane = tid & 63, wv = tid >> 6;
  int l15 = lane & 15, l4 = lane >> 4;
  int sseg = tid & 3;            // k-segment 0..3 (8 k's each)
  int srow = tid >> 2;           // 0..63
  const u16* a0p = A + (mBase + srow) * K + sseg * 8;
  const u16* a1p = a0p + (long)64 * K;
  bool colOK = (nBase + srow) < N;
  const u16* bp  = Wt + (long)nt * 64 * K + (long)srow * K + sseg * 8;

  f32x4 acc[2][4];
  #pragma unroll
  for (int i = 0; i < 2; i++)
    #pragma unroll
    for (int j = 0; j < 4; j++)
      acc[i][j] = (f32x4){0.f, 0.f, 0.f, 0.f};

  for (int k0 = 0; k0 < K; k0 += 32) {
    uint4 av0 = *(const uint4*)(a0p + k0);
    uint4 av1 = *(const uint4*)(a1p + k0);
    uint4 bv  = colOK ? *(const uint4*)(bp + k0) : make_uint4(0, 0, 0, 0);
    *(uint4*)&As[sseg][srow][0]      = av0;
    *(uint4*)&As[sseg][srow + 64][0] = av1;
    *(uint4*)&Bs[sseg][srow][0]      = bv;
    __syncthreads();
    bf16x8 af[2], bfr[4];
    af[0] = *(const bf16x8*)&As[l4][wv * 32 + l15][0];
    af[1] = *(const bf16x8*)&As[l4][wv * 32 + 16 + l15][0];
    #pragma unroll
    for (int j = 0; j < 4; j++)
      bfr[j] = *(const bf16x8*)&Bs[l4][j * 16 + l15][0];
    #pragma unroll
    for (int i = 0; i < 2; i++)
      #pragma unroll
      for (int j = 0; j < 4; j++)
        acc[i][j] = __builtin_amdgcn_mfma_f32_16x16x32_bf16(
            af[i], bfr[j], acc[i][j], 0, 0, 0);
    __syncthreads();
  }

  #pragma unroll
  for (int i = 0; i < 2; i++) {
    #pragma unroll
    for (int j = 0; j < 4; j++) {
      int n = nBase + j * 16 + l15;
      if (n < N) {
        #pragma unroll
        for (int r = 0; r < 4; r++) {
          long row = mBase + wv * 32 + i * 16 + l4 * 4 + r;
          float vv = acc[i][j][r];
          if (bias) vv += bias[n];
          if (RELU) vv = fmaxf(vv, 0.f);
          if (RES)  vv += resid[row * N + n];
          if (OBF) ((u16*)outp)[row * N + n] = f2bf(vv);
          else     ((float*)outp)[row * N + n] = vv;
        }
      }
    }
  }
}

// ---------------------------------------------------------------- attention
__global__ __launch_bounds__(256) void attn_k(const u16* __restrict__ q,
    const u16* __restrict__ k, const u16* __restrict__ v,
    u16* __restrict__ ao)
{
  __shared__ float qs[T_][64];
  __shared__ float kT[64][64];
  __shared__ float vs[T_][64];
  __shared__ float ps[T_][64];
  int tid = threadIdx.x;
  int bb = blockIdx.x / H_;
  int hh = blockIdx.x % H_;
  long base = ((long)bb * T_) * C_ + hh * HS_;

  for (int i = tid; i < T_ * 8; i += 256) {
    int t = i >> 3, d0 = (i & 7) << 3;
    long off = base + (long)t * C_ + d0;
    uint4 r; float f[8];
    r = *(const uint4*)(q + off);
    f[0]=bf2f(r.x&0xffffu); f[1]=bf2f(r.x>>16); f[2]=bf2f(r.y&0xffffu); f[3]=bf2f(r.y>>16);
    f[4]=bf2f(r.z&0xffffu); f[5]=bf2f(r.z>>16); f[6]=bf2f(r.w&0xffffu); f[7]=bf2f(r.w>>16);
    #pragma unroll
    for (int m = 0; m < 8; m++) qs[t][d0 + m] = f[m];
    r = *(const uint4*)(v + off);
    f[0]=bf2f(r.x&0xffffu); f[1]=bf2f(r.x>>16); f[2]=bf2f(r.y&0xffffu); f[3]=bf2f(r.y>>16);
    f[4]=bf2f(r.z&0xffffu); f[5]=bf2f(r.z>>16); f[6]=bf2f(r.w&0xffffu); f[7]=bf2f(r.w>>16);
    #pragma unroll
    for (int m = 0; m < 8; m++) vs[t][d0 + m] = f[m];
    r = *(const uint4*)(k + off);
    f[0]=bf2f(r.x&0xffffu); f[1]=bf2f(r.x>>16); f[2]=bf2f(r.y&0xffffu); f[3]=bf2f(r.y>>16);
    f[4]=bf2f(r.z&0xffffu); f[5]=bf2f(r.z>>16); f[6]=bf2f(r.w&0xffffu); f[7]=bf2f(r.w>>16);
    #pragma unroll
    for (int m = 0; m < 8; m++) kT[d0 + m][t] = f[m];
  }
  __syncthreads();

  for (int idx = tid; idx < T_ * T_; idx += 256) {
    int i = idx / T_, j = idx - i * T_;
    if (j <= i) {
      float acc = 0.f;
      #pragma unroll 16
      for (int d = 0; d < 64; d++) acc = fmaf(qs[i][d], kT[d][j], acc);
      ps[i][j] = acc * 0.125f;                    // HS^-0.5
    }
  }
  __syncthreads();

  int lane = tid & 63, wv = tid >> 6;
  for (int i = wv; i < T_; i += 4) {
    float val = (lane <= i) ? ps[i][lane] : -1e30f;
    float m = val;
    #pragma unroll
    for (int off = 32; off > 0; off >>= 1) m = fmaxf(m, __shfl_xor(m, off, 64));
    float e = (lane <= i) ? __expf(val - m) : 0.f;
    float s2 = e;
    #pragma unroll
    for (int off = 32; off > 0; off >>= 1) s2 += __shfl_xor(s2, off, 64);
    ps[i][lane] = e / s2;
  }
  __syncthreads();

  for (int g2 = tid; g2 < T_ * 16; g2 += 256) {
    int t = g2 >> 4, d0 = (g2 & 15) << 2;
    float a0 = 0, a1 = 0, a2 = 0, a3 = 0;
    for (int j = 0; j < T_; j++) {
      float p = ps[t][j];
      float4 v4 = *(const float4*)&vs[j][d0];
      a0 = fmaf(p, v4.x, a0); a1 = fmaf(p, v4.y, a1);
      a2 = fmaf(p, v4.z, a2); a3 = fmaf(p, v4.w, a3);
    }
    long off = base + (long)t * C_ + d0;
    uint2 o2;
    o2.x = (u32)f2bf(a0) | ((u32)f2bf(a1) << 16);
    o2.y = (u32)f2bf(a2) | ((u32)f2bf(a3) << 16);
    *(uint2*)(ao + off) = o2;
  }
}

// ---------------------------------------------------------------- launch
extern "C" void kernel_launch(void* const* d_in, const int* in_sizes, int n_in,
                              void* d_out, int out_size, void* d_ws, size_t ws_size,
                              hipStream_t stream)
{
  const int*   ctx  = (const int*)  d_in[0];
  const float* tok  = (const float*)d_in[1];
  const float* pos  = (const float*)d_in[2];
  const float* wq   = (const float*)d_in[3];
  const float* wk   = (const float*)d_in[4];
  const float* wv   = (const float*)d_in[5];
  const float* wo   = (const float*)d_in[6];
  const float* bo   = (const float*)d_in[7];
  const float* ln1g = (const float*)d_in[8];
  const float* ln1b = (const float*)d_in[9];
  const float* ln2g = (const float*)d_in[10];
  const float* ln2b = (const float*)d_in[11];
  const float* w1   = (const float*)d_in[12];
  const float* b1   = (const float*)d_in[13];
  const float* w2   = (const float*)d_in[14];
  const float* b2   = (const float*)d_in[15];
  const float* lnfg = (const float*)d_in[16];
  const float* lnfb = (const float*)d_in[17];
  const float* lmw  = (const float*)d_in[18];
  const float* lmb  = (const float*)d_in[19];
  float* out = (float*)d_out;

  // ---- bf16 transposed weights at front of ws (element counts) ----
  const long nQKV = (long)L_ * H_ * C_ * HS_;    //  884736 each
  const long nWO  = (long)L_ * C_ * C_;          //  884736
  const long nW1  = (long)L_ * C_ * FF_;         // 3538944
  const long nLM  = (long)C_ * V_;               //   24960
  u16* wqT = (u16*)d_ws;
  u16* wkT = wqT + nQKV;
  u16* wvT = wkT + nQKV;
  u16* woT = wvT + nQKV;
  u16* w1T = woT + nWO;
  u16* w2T = w1T + nW1;
  u16* lmT = w2T + nW1;
  const size_t wbytes = (size_t)(nQKV * 3 + nWO + nW1 * 2 + nLM) * 2; // 21,283,584

  // chunk selection: weights + 7U must fit
  int chunkB = 16;
  {
    const int cand[] = {1024, 512, 256, 128, 64, 32, 16};
    for (int i = 0; i < 7; i++) {
      size_t U = (size_t)cand[i] * T_ * C_ * 2;
      if (wbytes + 7 * U <= ws_size) { chunkB = cand[i]; break; }
    }
  }
  const long BTc = (long)chunkB * T_;
  char* wsb = (char*)d_ws + wbytes;
  const size_t U = (size_t)BTc * C_ * 2;
  float* x   = (float*)wsb;              // 2U
  u16*   h   = (u16*)(wsb + 2 * U);      // 1U
  char*  reg = wsb + 3 * U;              // 4U
  u16* qb = (u16*)reg;
  u16* kb = (u16*)(reg + U);
  u16* vb = (u16*)(reg + 2 * U);
  u16* ab = qb;                          // alias: safe (attn ordering)
  u16* fb = (u16*)reg;                   // alias: k/v dead before MLP

  // ---- convert weights (every call; same work each time) ----
  {
    dim3 tb(32, 8);
    tconv_k<<<dim3(2, 12, L_ * H_), tb, 0, stream>>>(wq, wqT, C_, HS_,
        (long)C_ * HS_, (long)HS_ * C_);
    tconv_k<<<dim3(2, 12, L_ * H_), tb, 0, stream>>>(wk, wkT, C_, HS_,
        (long)C_ * HS_, (long)HS_ * C_);
    tconv_k<<<dim3(2, 12, L_ * H_), tb, 0, stream>>>(wv, wvT, C_, HS_,
        (long)C_ * HS_, (long)HS_ * C_);
    tconv_k<<<dim3(12, 12, L_), tb, 0, stream>>>(wo, woT, C_, C_,
        (long)C_ * C_, (long)C_ * C_);
    tconv_k<<<dim3(48, 12, L_), tb, 0, stream>>>(w1, w1T, C_, FF_,
        (long)C_ * FF_, (long)C_ * FF_);
    tconv_k<<<dim3(12, 48, L_), tb, 0, stream>>>(w2, w2T, FF_, C_,
        (long)FF_ * C_, (long)FF_ * C_);
    tconv_k<<<dim3(3, 12, 1), tb, 0, stream>>>(lmw, lmT, C_, V_,
        (long)C_ * V_, (long)C_ * V_);
  }

  const long wqL = (long)H_ * HS_ * C_;          // per-layer stride (qkv, wo)
  const long w1L = (long)C_ * FF_;               // per-layer stride (w1, w2)
  dim3 blk(256);
  dim3 gEmb((u32)(BTc * C_ / 4 / 256));
  dim3 gLN((u32)(BTc / 4));
  dim3 g6(C_ / 64, (u32)(BTc / 128));            // (6, Mtiles)
  dim3 g24(FF_ / 64, (u32)(BTc / 128));          // (24, Mtiles)
  dim3 gHd(2, (u32)(BTc / 128));
  dim3 gAt((u32)(chunkB * H_));

  for (int c0 = 0; c0 < B_; c0 += chunkB) {
    const long tok0 = (long)c0 * T_;
    const int* ctxc = ctx + tok0;
    float* outc = out + tok0 * V_;

    embed_k<<<gEmb, blk, 0, stream>>>(ctxc, tok, pos, x);

    for (int l = 0; l < L_; l++) {
      ln_k<<<gLN, blk, 0, stream>>>(x, ln1g + l * C_, ln1b + l * C_, h);
      gemm_mfma<0,0,1><<<g6, blk, 0, stream>>>(h, wqT + l * wqL,
          nullptr, nullptr, qb, C_, C_);
      gemm_mfma<0,0,1><<<g6, blk, 0, stream>>>(h, wkT + l * wqL,
          nullptr, nullptr, kb, C_, C_);
      gemm_mfma<0,0,1><<<g6, blk, 0, stream>>>(h, wvT + l * wqL,
          nullptr, nullptr, vb, C_, C_);
      attn_k<<<gAt, blk, 0, stream>>>(qb, kb, vb, ab);
      gemm_mfma<0,1,0><<<g6, blk, 0, stream>>>(ab, woT + l * wqL,
          bo + l * C_, x, x, C_, C_);
      ln_k<<<gLN, blk, 0, stream>>>(x, ln2g + l * C_, ln2b + l * C_, h);
      gemm_mfma<1,0,1><<<g24, blk, 0, stream>>>(h, w1T + l * w1L,
          b1 + l * FF_, nullptr, fb, FF_, C_);
      gemm_mfma<0,1,0><<<g6, blk, 0, stream>>>(fb, w2T + l * w1L,
          b2 + l * C_, x, x, C_, FF_);
    }

    ln_k<<<gLN, blk, 0, stream>>>(x, lnfg, lnfb, h);
    gemm_mfma<0,0,0><<<gHd, blk, 0, stream>>>(h, lmT, lmb, nullptr,
        outc, V_, C_);
  }
}

// Round 4
// 12289.421 us; speedup vs baseline: 3.1194x; 1.0821x over previous
//
#include <hip/hip_runtime.h>

// ---------------------------------------------------------------------------
// SimpleGPT forward on MI355X. Round 4: m97-style GEMM (128x128 tile,
// global_load_lds 16B staging) + fused QKV.
//   - weights pre-transposed+converted to bf16 in ws front (21.3 MB);
//     QKV fused into one Wt [1152][384] per layer (rows = output cols,
//     q|k|v sections, head-major inside each section).
//   - gemm128: BM=BN=128 BK=32, 256 thr; per k-step each wave: 4x
//     global_load_lds(16B) issues, 10x ds_read_b128, 16x mfma_16x16x32_bf16.
//     LDS [kseg][row][8]: global_load_lds dest is wave-uniform base +
//     lane*16 -> slot s = half*256 + wave*64 + lane, kseg=s>>7, row=s&127.
//   - head gemm (N=65) keeps R3 BN=64 ds-write path.
//   - batch-chunked; chunkB multiple of 32 so BTc%128==0. scratch 7U + weights.
// ---------------------------------------------------------------------------

#define B_  2048
#define T_  60
#define C_  384
#define H_  6
#define HS_ 64
#define L_  6
#define FF_ 1536
#define V_  65

typedef unsigned int  u32;
typedef unsigned short u16;
typedef short bf16x8 __attribute__((ext_vector_type(8)));
typedef float f32x4  __attribute__((ext_vector_type(4)));

__device__ __forceinline__ float bf2f(u32 u) {
  return __uint_as_float(u << 16);
}
__device__ __forceinline__ u16 f2bf(float f) {
  u32 u = __float_as_uint(f);
  u = u + 0x7FFFu + ((u >> 16) & 1u);   // RNE; inputs are finite
  return (u16)(u >> 16);
}

__device__ __forceinline__ void gload_lds16(const u16* g, u16* l) {
  __builtin_amdgcn_global_load_lds(
      (const __attribute__((address_space(1))) void*)g,
      (__attribute__((address_space(3))) void*)l, 16, 0, 0);
}

// ------------------------------------------------ weight transpose+convert
// src fp32 [K][N] (mats indexed z: l = z/nH, h = z%nH) -> dst bf16 [N][K]
// at dst + l*sL + h*sH.
__global__ void tconv_k(const float* __restrict__ src, u16* __restrict__ dst,
                        int K, int N, long srcStride, int nH, long sL, long sH)
{
  __shared__ float t[32][33];
  int z = blockIdx.z;
  int l = z / nH, hh = z % nH;
  const float* s = src + (long)z * srcStride;
  u16* d = dst + l * sL + hh * sH;
  int n0 = blockIdx.x * 32, k0 = blockIdx.y * 32;
  for (int yy = threadIdx.y; yy < 32; yy += 8) {
    int k = k0 + yy, n = n0 + threadIdx.x;
    t[yy][threadIdx.x] = (k < K && n < N) ? s[(long)k * N + n] : 0.f;
  }
  __syncthreads();
  for (int yy = threadIdx.y; yy < 32; yy += 8) {
    int n = n0 + yy, k = k0 + threadIdx.x;
    if (n < N && k < K) d[(long)n * K + k] = f2bf(t[threadIdx.x][yy]);
  }
}

// ---------------------------------------------------------------- embedding
__global__ __launch_bounds__(256) void embed_k(const int* __restrict__ ctx,
    const float* __restrict__ tok, const float* __restrict__ pos,
    float* __restrict__ x)
{
  int idx = blockIdx.x * 256 + threadIdx.x;
  int row = idx / (C_ / 4);
  int c   = (idx % (C_ / 4)) * 4;
  int t   = row % T_;
  int tk  = ctx[row];
  float4 a = *(const float4*)(tok + (long)tk * C_ + c);
  float4 p = *(const float4*)(pos + (long)t  * C_ + c);
  float4 o = make_float4(a.x + p.x, a.y + p.y, a.z + p.z, a.w + p.w);
  *(float4*)(x + (long)idx * 4) = o;
}

// ---------------------------------------------------------------- layernorm
__global__ __launch_bounds__(256) void ln_k(const float* __restrict__ x,
    const float* __restrict__ g, const float* __restrict__ b,
    u16* __restrict__ h)
{
  int lane = threadIdx.x & 63;
  int wv   = threadIdx.x >> 6;
  long row = (long)blockIdx.x * 4 + wv;
  const float* xr = x + row * C_;
  int c0 = lane * 6;
  float v0[6];
  #pragma unroll
  for (int i = 0; i < 6; i++) v0[i] = xr[c0 + i];
  float s = 0.f, sq = 0.f;
  #pragma unroll
  for (int i = 0; i < 6; i++) { s += v0[i]; sq += v0[i] * v0[i]; }
  #pragma unroll
  for (int off = 32; off > 0; off >>= 1) {
    s  += __shfl_xor(s,  off, 64);
    sq += __shfl_xor(sq, off, 64);
  }
  float mu  = s * (1.f / C_);
  float var = sq * (1.f / C_) - mu * mu;
  float rs  = rsqrtf(var + 1e-5f);
  u16* hr = h + row * C_;
  #pragma unroll
  for (int i = 0; i < 6; i++) {
    float hv = (v0[i] - mu) * rs * g[c0 + i] + b[c0 + i];
    hr[c0 + i] = f2bf(hv);
  }
}

// ------------------------------------------------------------- MFMA GEMM 128
// out[M,N] = act(A[M,K](bf16) @ Wt^T + bias) [+ resid]; Wt bf16 [N][K].
// Requires M%128==0, N%128==0, K%32==0.
template<int RELU, int RES, int OBF>
__global__ __launch_bounds__(256) void gemm128(const u16* __restrict__ A,
    const u16* __restrict__ Wt, const float* __restrict__ bias,
    const float* __restrict__ resid, void* __restrict__ outp, int N, int K)
{
  __shared__ __align__(16) u16 As[4][128][8];   // [kseg][row][kj]  8 KB
  __shared__ __align__(16) u16 Bs[4][128][8];   // [kseg][col][kj]  8 KB
  int tid  = threadIdx.x;
  int nBase = blockIdx.x * 128;
  long mBase = (long)blockIdx.y * 128;
  int lane = tid & 63, wv = tid >> 6;
  int l15 = lane & 15, l4 = lane >> 4;

  // staging geometry: slot s = half*256 + wv*64 + lane; kseg=s>>7, row=s&127
  int s0 = wv * 64 + lane;            // half 0
  int s1 = s0 + 256;                  // half 1
  int r0s = s0 & 127, k0s = s0 >> 7;
  int r1s = s1 & 127, k1s = s1 >> 7;
  const u16* a0p = A + (mBase + r0s) * K + k0s * 8;
  const u16* a1p = A + (mBase + r1s) * K + k1s * 8;
  const u16* b0p = Wt + (long)(nBase + r0s) * K + k0s * 8;
  const u16* b1p = Wt + (long)(nBase + r1s) * K + k1s * 8;
  u16* ldsA0 = &As[0][0][0] + (wv * 64) * 8;        // wave-uniform
  u16* ldsA1 = ldsA0 + 256 * 8;
  u16* ldsB0 = &Bs[0][0][0] + (wv * 64) * 8;
  u16* ldsB1 = ldsB0 + 256 * 8;

  f32x4 acc[2][8];
  #pragma unroll
  for (int i = 0; i < 2; i++)
    #pragma unroll
    for (int j = 0; j < 8; j++)
      acc[i][j] = (f32x4){0.f, 0.f, 0.f, 0.f};

  for (int k0 = 0; k0 < K; k0 += 32) {
    gload_lds16(a0p + k0, ldsA0);
    gload_lds16(a1p + k0, ldsA1);
    gload_lds16(b0p + k0, ldsB0);
    gload_lds16(b1p + k0, ldsB1);
    __syncthreads();
    bf16x8 af[2], bfr[8];
    af[0] = *(const bf16x8*)&As[l4][wv * 32 + l15][0];
    af[1] = *(const bf16x8*)&As[l4][wv * 32 + 16 + l15][0];
    #pragma unroll
    for (int j = 0; j < 8; j++)
      bfr[j] = *(const bf16x8*)&Bs[l4][j * 16 + l15][0];
    #pragma unroll
    for (int i = 0; i < 2; i++)
      #pragma unroll
      for (int j = 0; j < 8; j++)
        acc[i][j] = __builtin_amdgcn_mfma_f32_16x16x32_bf16(
            af[i], bfr[j], acc[i][j], 0, 0, 0);
    __syncthreads();
  }

  #pragma unroll
  for (int i = 0; i < 2; i++) {
    #pragma unroll
    for (int j = 0; j < 8; j++) {
      int n = nBase + j * 16 + l15;
      float bv = bias ? bias[n] : 0.f;
      #pragma unroll
      for (int r = 0; r < 4; r++) {
        long row = mBase + wv * 32 + i * 16 + l4 * 4 + r;
        float vv = acc[i][j][r] + bv;
        if (RELU) vv = fmaxf(vv, 0.f);
        if (RES)  vv += resid[row * N + n];
        if (OBF) ((u16*)outp)[row * N + n] = f2bf(vv);
        else     ((float*)outp)[row * N + n] = vv;
      }
    }
  }
}

// ------------------------------------------------------------- head GEMM
// BN=64 ds-write path (N=65 needs guards). BM=128, BK=32.
template<int OBF>
__global__ __launch_bounds__(256) void gemm_head(const u16* __restrict__ A,
    const u16* __restrict__ Wt, const float* __restrict__ bias,
    void* __restrict__ outp, int N, int K)
{
  __shared__ __align__(16) u16 As[4][128][8];
  __shared__ __align__(16) u16 Bs[4][64][8];
  int tid  = threadIdx.x;
  int nt   = blockIdx.x;
  int nBase = nt * 64;
  long mBase = (long)blockIdx.y * 128;
  int lane = tid & 63, wv = tid >> 6;
  int l15 = lane & 15, l4 = lane >> 4;
  int sseg = tid & 3;
  int srow = tid >> 2;
  const u16* a0p = A + (mBase + srow) * K + sseg * 8;
  const u16* a1p = a0p + (long)64 * K;
  bool colOK = (nBase + srow) < N;
  const u16* bp  = Wt + (long)(nBase + srow) * K + sseg * 8;

  f32x4 acc[2][4];
  #pragma unroll
  for (int i = 0; i < 2; i++)
    #pragma unroll
    for (int j = 0; j < 4; j++)
      acc[i][j] = (f32x4){0.f, 0.f, 0.f, 0.f};

  for (int k0 = 0; k0 < K; k0 += 32) {
    uint4 av0 = *(const uint4*)(a0p + k0);
    uint4 av1 = *(const uint4*)(a1p + k0);
    uint4 bv  = colOK ? *(const uint4*)(bp + k0) : make_uint4(0, 0, 0, 0);
    *(uint4*)&As[sseg][srow][0]      = av0;
    *(uint4*)&As[sseg][srow + 64][0] = av1;
    *(uint4*)&Bs[sseg][srow][0]      = bv;
    __syncthreads();
    bf16x8 af[2], bfr[4];
    af[0] = *(const bf16x8*)&As[l4][wv * 32 + l15][0];
    af[1] = *(const bf16x8*)&As[l4][wv * 32 + 16 + l15][0];
    #pragma unroll
    for (int j = 0; j < 4; j++)
      bfr[j] = *(const bf16x8*)&Bs[l4][j * 16 + l15][0];
    #pragma unroll
    for (int i = 0; i < 2; i++)
      #pragma unroll
      for (int j = 0; j < 4; j++)
        acc[i][j] = __builtin_amdgcn_mfma_f32_16x16x32_bf16(
            af[i], bfr[j], acc[i][j], 0, 0, 0);
    __syncthreads();
  }

  #pragma unroll
  for (int i = 0; i < 2; i++) {
    #pragma unroll
    for (int j = 0; j < 4; j++) {
      int n = nBase + j * 16 + l15;
      if (n < N) {
        #pragma unroll
        for (int r = 0; r < 4; r++) {
          long row = mBase + wv * 32 + i * 16 + l4 * 4 + r;
          float vv = acc[i][j][r];
          if (bias) vv += bias[n];
          if (OBF) ((u16*)outp)[row * N + n] = f2bf(vv);
          else     ((float*)outp)[row * N + n] = vv;
        }
      }
    }
  }
}

// ---------------------------------------------------------------- attention
// qkv bf16 [BTc][1152] (q|k|v sections, head-major inside each);
// ao bf16 [BTc][384].
__global__ __launch_bounds__(256) void attn_k(const u16* __restrict__ qkv,
    u16* __restrict__ ao)
{
  __shared__ float qs[T_][64];
  __shared__ float kT[64][64];
  __shared__ float vs[T_][64];
  __shared__ float ps[T_][64];
  int tid = threadIdx.x;
  int bb = blockIdx.x / H_;
  int hh = blockIdx.x % H_;
  long base = ((long)bb * T_) * 1152 + hh * HS_;

  for (int i = tid; i < T_ * 8; i += 256) {
    int t = i >> 3, d0 = (i & 7) << 3;
    long off = base + (long)t * 1152 + d0;
    uint4 r; float f[8];
    r = *(const uint4*)(qkv + off);               // q section
    f[0]=bf2f(r.x&0xffffu); f[1]=bf2f(r.x>>16); f[2]=bf2f(r.y&0xffffu); f[3]=bf2f(r.y>>16);
    f[4]=bf2f(r.z&0xffffu); f[5]=bf2f(r.z>>16); f[6]=bf2f(r.w&0xffffu); f[7]=bf2f(r.w>>16);
    #pragma unroll
    for (int m = 0; m < 8; m++) qs[t][d0 + m] = f[m];
    r = *(const uint4*)(qkv + off + 768);         // v section
    f[0]=bf2f(r.x&0xffffu); f[1]=bf2f(r.x>>16); f[2]=bf2f(r.y&0xffffu); f[3]=bf2f(r.y>>16);
    f[4]=bf2f(r.z&0xffffu); f[5]=bf2f(r.z>>16); f[6]=bf2f(r.w&0xffffu); f[7]=bf2f(r.w>>16);
    #pragma unroll
    for (int m = 0; m < 8; m++) vs[t][d0 + m] = f[m];
    r = *(const uint4*)(qkv + off + 384);         // k section
    f[0]=bf2f(r.x&0xffffu); f[1]=bf2f(r.x>>16); f[2]=bf2f(r.y&0xffffu); f[3]=bf2f(r.y>>16);
    f[4]=bf2f(r.z&0xffffu); f[5]=bf2f(r.z>>16); f[6]=bf2f(r.w&0xffffu); f[7]=bf2f(r.w>>16);
    #pragma unroll
    for (int m = 0; m < 8; m++) kT[d0 + m][t] = f[m];
  }
  __syncthreads();

  for (int idx = tid; idx < T_ * T_; idx += 256) {
    int i = idx / T_, j = idx - i * T_;
    if (j <= i) {
      float acc = 0.f;
      #pragma unroll 16
      for (int d = 0; d < 64; d++) acc = fmaf(qs[i][d], kT[d][j], acc);
      ps[i][j] = acc * 0.125f;
    }
  }
  __syncthreads();

  int lane = tid & 63, wv = tid >> 6;
  for (int i = wv; i < T_; i += 4) {
    float val = (lane <= i) ? ps[i][lane] : -1e30f;
    float m = val;
    #pragma unroll
    for (int off = 32; off > 0; off >>= 1) m = fmaxf(m, __shfl_xor(m, off, 64));
    float e = (lane <= i) ? __expf(val - m) : 0.f;
    float s2 = e;
    #pragma unroll
    for (int off = 32; off > 0; off >>= 1) s2 += __shfl_xor(s2, off, 64);
    ps[i][lane] = e / s2;
  }
  __syncthreads();

  long obase = ((long)bb * T_) * C_ + hh * HS_;
  for (int g2 = tid; g2 < T_ * 16; g2 += 256) {
    int t = g2 >> 4, d0 = (g2 & 15) << 2;
    float a0 = 0, a1 = 0, a2 = 0, a3 = 0;
    for (int j = 0; j < T_; j++) {
      float p = ps[t][j];
      float4 v4 = *(const float4*)&vs[j][d0];
      a0 = fmaf(p, v4.x, a0); a1 = fmaf(p, v4.y, a1);
      a2 = fmaf(p, v4.z, a2); a3 = fmaf(p, v4.w, a3);
    }
    long off = obase + (long)t * C_ + d0;
    uint2 o2;
    o2.x = (u32)f2bf(a0) | ((u32)f2bf(a1) << 16);
    o2.y = (u32)f2bf(a2) | ((u32)f2bf(a3) << 16);
    *(uint2*)(ao + off) = o2;
  }
}

// ---------------------------------------------------------------- launch
extern "C" void kernel_launch(void* const* d_in, const int* in_sizes, int n_in,
                              void* d_out, int out_size, void* d_ws, size_t ws_size,
                              hipStream_t stream)
{
  const int*   ctx  = (const int*)  d_in[0];
  const float* tok  = (const float*)d_in[1];
  const float* pos  = (const float*)d_in[2];
  const float* wq   = (const float*)d_in[3];
  const float* wk   = (const float*)d_in[4];
  const float* wv   = (const float*)d_in[5];
  const float* wo   = (const float*)d_in[6];
  const float* bo   = (const float*)d_in[7];
  const float* ln1g = (const float*)d_in[8];
  const float* ln1b = (const float*)d_in[9];
  const float* ln2g = (const float*)d_in[10];
  const float* ln2b = (const float*)d_in[11];
  const float* w1   = (const float*)d_in[12];
  const float* b1   = (const float*)d_in[13];
  const float* w2   = (const float*)d_in[14];
  const float* b2   = (const float*)d_in[15];
  const float* lnfg = (const float*)d_in[16];
  const float* lnfb = (const float*)d_in[17];
  const float* lmw  = (const float*)d_in[18];
  const float* lmb  = (const float*)d_in[19];
  float* out = (float*)d_out;

  // ---- bf16 transposed weights at front of ws (element counts) ----
  const long nQKV = (long)L_ * H_ * C_ * HS_;    //  884736 each
  const long nWO  = (long)L_ * C_ * C_;
  const long nW1  = (long)L_ * C_ * FF_;
  const long nLM  = (long)C_ * V_;
  u16* wqkvT = (u16*)d_ws;                       // [L][1152][384]
  u16* woT = wqkvT + 3 * nQKV;
  u16* w1T = woT + nWO;
  u16* w2T = w1T + nW1;
  u16* lmT = w2T + nW1;
  const size_t wbytes = (size_t)(nQKV * 3 + nWO + nW1 * 2 + nLM) * 2;

  // chunk selection: chunkB multiple of 32 (BTc%128==0); weights + 7U fit
  int chunkB = 32;
  {
    const int cand[] = {2048, 1024, 512, 256, 128, 64, 32};
    for (int i = 0; i < 7; i++) {
      size_t U = (size_t)cand[i] * T_ * C_ * 2;
      if (wbytes + 7 * U <= ws_size) { chunkB = cand[i]; break; }
    }
  }
  const long BTc = (long)chunkB * T_;
  char* wsb = (char*)d_ws + wbytes;
  const size_t U = (size_t)BTc * C_ * 2;
  float* x    = (float*)wsb;             // 2U
  u16*   h    = (u16*)(wsb + 2 * U);     // 1U
  char*  reg  = wsb + 3 * U;             // 4U: qkv(3U) + ab(1U); fb aliases
  u16* qkvb = (u16*)reg;
  u16* ab   = (u16*)(reg + 3 * U);
  u16* fb   = (u16*)reg;                 // alias: qkv/ab dead before MLP

  // ---- convert weights (same work every call) ----
  {
    dim3 tb(32, 8);
    const long sL = 1152L * 384, sH = 64L * 384, sec = 384L * 384;
    tconv_k<<<dim3(2, 12, L_ * H_), tb, 0, stream>>>(wq, wqkvT,
        C_, HS_, (long)C_ * HS_, H_, sL, sH);
    tconv_k<<<dim3(2, 12, L_ * H_), tb, 0, stream>>>(wk, wqkvT + sec,
        C_, HS_, (long)C_ * HS_, H_, sL, sH);
    tconv_k<<<dim3(2, 12, L_ * H_), tb, 0, stream>>>(wv, wqkvT + 2 * sec,
        C_, HS_, (long)C_ * HS_, H_, sL, sH);
    tconv_k<<<dim3(12, 12, L_), tb, 0, stream>>>(wo, woT,
        C_, C_, (long)C_ * C_, 1, (long)C_ * C_, 0);
    tconv_k<<<dim3(48, 12, L_), tb, 0, stream>>>(w1, w1T,
        C_, FF_, (long)C_ * FF_, 1, (long)C_ * FF_, 0);
    tconv_k<<<dim3(12, 48, L_), tb, 0, stream>>>(w2, w2T,
        FF_, C_, (long)FF_ * C_, 1, (long)FF_ * C_, 0);
    tconv_k<<<dim3(3, 12, 1), tb, 0, stream>>>(lmw, lmT,
        C_, V_, (long)C_ * V_, 1, 0, 0);
  }

  const long qkvL = 1152L * 384;                 // per-layer strides
  const long woL  = (long)C_ * C_;
  const long w1L  = (long)C_ * FF_;
  dim3 blk(256);
  dim3 gEmb((u32)(BTc * C_ / 4 / 256));
  dim3 gLN((u32)(BTc / 4));
  u32 mT = (u32)(BTc / 128);
  dim3 gQKV(9, mT), gWO(3, mT), gW1(12, mT), gW2(3, mT);
  dim3 gHd(2, mT);
  dim3 gAt((u32)(chunkB * H_));

  for (int c0 = 0; c0 < B_; c0 += chunkB) {
    const long tok0 = (long)c0 * T_;
    const int* ctxc = ctx + tok0;
    float* outc = out + tok0 * V_;

    embed_k<<<gEmb, blk, 0, stream>>>(ctxc, tok, pos, x);

    for (int l = 0; l < L_; l++) {
      ln_k<<<gLN, blk, 0, stream>>>(x, ln1g + l * C_, ln1b + l * C_, h);
      gemm128<0,0,1><<<gQKV, blk, 0, stream>>>(h, wqkvT + l * qkvL,
          nullptr, nullptr, qkvb, 1152, C_);
      attn_k<<<gAt, blk, 0, stream>>>(qkvb, ab);
      gemm128<0,1,0><<<gWO, blk, 0, stream>>>(ab, woT + l * woL,
          bo + l * C_, x, x, C_, C_);
      ln_k<<<gLN, blk, 0, stream>>>(x, ln2g + l * C_, ln2b + l * C_, h);
      gemm128<1,0,1><<<gW1, blk, 0, stream>>>(h, w1T + l * w1L,
          b1 + l * FF_, nullptr, fb, FF_, C_);
      gemm128<0,1,0><<<gW2, blk, 0, stream>>>(fb, w2T + l * w1L,
          b2 + l * C_, x, x, C_, FF_);
    }

    ln_k<<<gLN, blk, 0, stream>>>(x, lnfg, lnfb, h);
    gemm_head<0><<<gHd, blk, 0, stream>>>(h, lmT, lmb, outc, V_, C_);
  }
}

// Round 5
// 7110.271 us; speedup vs baseline: 5.3916x; 1.7284x over previous
//
#include <hip/hip_runtime.h>

// ---------------------------------------------------------------------------
// SimpleGPT forward on MI355X. Round 5:
//   - gemm128 reverted to ds_write_b128 staging (global_load_lds over-fetched
//     3.5x at K=384: 768B-stride lanes, 18ms outlier dispatch in R4 profile).
//   - attn_k rewritten with MFMA: QK^T and PV via mfma_f32_16x16x32_bf16,
//     softmax in C-layout regs (width-16 shuffles), P through LDS in bf16.
//     LDS rows stride 72 (b128 frag reads 2-way-free), 36.9KB -> 4 blk/CU.
//   - weights pre-transposed bf16 (QKV fused [1152][384] per layer).
// ---------------------------------------------------------------------------

#define B_  2048
#define T_  60
#define C_  384
#define H_  6
#define HS_ 64
#define L_  6
#define FF_ 1536
#define V_  65

typedef unsigned int  u32;
typedef unsigned short u16;
typedef short bf16x8 __attribute__((ext_vector_type(8)));
typedef float f32x4  __attribute__((ext_vector_type(4)));

__device__ __forceinline__ float bf2f(u32 u) {
  return __uint_as_float(u << 16);
}
__device__ __forceinline__ u16 f2bf(float f) {
  u32 u = __float_as_uint(f);
  u = u + 0x7FFFu + ((u >> 16) & 1u);   // RNE; inputs are finite
  return (u16)(u >> 16);
}

// ------------------------------------------------ weight transpose+convert
__global__ void tconv_k(const float* __restrict__ src, u16* __restrict__ dst,
                        int K, int N, long srcStride, int nH, long sL, long sH)
{
  __shared__ float t[32][33];
  int z = blockIdx.z;
  int l = z / nH, hh = z % nH;
  const float* s = src + (long)z * srcStride;
  u16* d = dst + l * sL + hh * sH;
  int n0 = blockIdx.x * 32, k0 = blockIdx.y * 32;
  for (int yy = threadIdx.y; yy < 32; yy += 8) {
    int k = k0 + yy, n = n0 + threadIdx.x;
    t[yy][threadIdx.x] = (k < K && n < N) ? s[(long)k * N + n] : 0.f;
  }
  __syncthreads();
  for (int yy = threadIdx.y; yy < 32; yy += 8) {
    int n = n0 + yy, k = k0 + threadIdx.x;
    if (n < N && k < K) d[(long)n * K + k] = f2bf(t[threadIdx.x][yy]);
  }
}

// ---------------------------------------------------------------- embedding
__global__ __launch_bounds__(256) void embed_k(const int* __restrict__ ctx,
    const float* __restrict__ tok, const float* __restrict__ pos,
    float* __restrict__ x)
{
  int idx = blockIdx.x * 256 + threadIdx.x;
  int row = idx / (C_ / 4);
  int c   = (idx % (C_ / 4)) * 4;
  int t   = row % T_;
  int tk  = ctx[row];
  float4 a = *(const float4*)(tok + (long)tk * C_ + c);
  float4 p = *(const float4*)(pos + (long)t  * C_ + c);
  float4 o = make_float4(a.x + p.x, a.y + p.y, a.z + p.z, a.w + p.w);
  *(float4*)(x + (long)idx * 4) = o;
}

// ---------------------------------------------------------------- layernorm
__global__ __launch_bounds__(256) void ln_k(const float* __restrict__ x,
    const float* __restrict__ g, const float* __restrict__ b,
    u16* __restrict__ h)
{
  int lane = threadIdx.x & 63;
  int wv   = threadIdx.x >> 6;
  long row = (long)blockIdx.x * 4 + wv;
  const float* xr = x + row * C_;
  int c0 = lane * 6;
  float v0[6];
  #pragma unroll
  for (int i = 0; i < 6; i++) v0[i] = xr[c0 + i];
  float s = 0.f, sq = 0.f;
  #pragma unroll
  for (int i = 0; i < 6; i++) { s += v0[i]; sq += v0[i] * v0[i]; }
  #pragma unroll
  for (int off = 32; off > 0; off >>= 1) {
    s  += __shfl_xor(s,  off, 64);
    sq += __shfl_xor(sq, off, 64);
  }
  float mu  = s * (1.f / C_);
  float var = sq * (1.f / C_) - mu * mu;
  float rs  = rsqrtf(var + 1e-5f);
  u16* hr = h + row * C_;
  #pragma unroll
  for (int i = 0; i < 6; i++) {
    float hv = (v0[i] - mu) * rs * g[c0 + i] + b[c0 + i];
    hr[c0 + i] = f2bf(hv);
  }
}

// ------------------------------------------------------------- MFMA GEMM 128
// out[M,N] = act(A[M,K](bf16) @ Wt^T + bias) [+ resid]; Wt bf16 [N][K].
// Requires M%128==0, N%128==0, K%32==0. ds_write_b128 staging.
template<int RELU, int RES, int OBF>
__global__ __launch_bounds__(256) void gemm128(const u16* __restrict__ A,
    const u16* __restrict__ Wt, const float* __restrict__ bias,
    const float* __restrict__ resid, void* __restrict__ outp, int N, int K)
{
  __shared__ __align__(16) u16 As[4][128][8];   // [kseg][row][kj]  8 KB
  __shared__ __align__(16) u16 Bs[4][128][8];   // [kseg][col][kj]  8 KB
  int tid  = threadIdx.x;
  int nBase = blockIdx.x * 128;
  long mBase = (long)blockIdx.y * 128;
  int lane = tid & 63, wv = tid >> 6;
  int l15 = lane & 15, l4 = lane >> 4;
  int sseg = tid & 3;
  int srow = tid >> 2;
  const u16* aP = A + (mBase + srow) * K + sseg * 8;
  const u16* bP = Wt + ((long)nBase + srow) * K + sseg * 8;

  f32x4 acc[2][8];
  #pragma unroll
  for (int i = 0; i < 2; i++)
    #pragma unroll
    for (int j = 0; j < 8; j++)
      acc[i][j] = (f32x4){0.f, 0.f, 0.f, 0.f};

  for (int k0 = 0; k0 < K; k0 += 32) {
    uint4 a0 = *(const uint4*)(aP + k0);
    uint4 a1 = *(const uint4*)(aP + (long)64 * K + k0);
    uint4 b0 = *(const uint4*)(bP + k0);
    uint4 b1 = *(const uint4*)(bP + (long)64 * K + k0);
    *(uint4*)&As[sseg][srow][0]      = a0;
    *(uint4*)&As[sseg][srow + 64][0] = a1;
    *(uint4*)&Bs[sseg][srow][0]      = b0;
    *(uint4*)&Bs[sseg][srow + 64][0] = b1;
    __syncthreads();
    bf16x8 af[2], bfr[8];
    af[0] = *(const bf16x8*)&As[l4][wv * 32 + l15][0];
    af[1] = *(const bf16x8*)&As[l4][wv * 32 + 16 + l15][0];
    #pragma unroll
    for (int j = 0; j < 8; j++)
      bfr[j] = *(const bf16x8*)&Bs[l4][j * 16 + l15][0];
    #pragma unroll
    for (int i = 0; i < 2; i++)
      #pragma unroll
      for (int j = 0; j < 8; j++)
        acc[i][j] = __builtin_amdgcn_mfma_f32_16x16x32_bf16(
            af[i], bfr[j], acc[i][j], 0, 0, 0);
    __syncthreads();
  }

  #pragma unroll
  for (int i = 0; i < 2; i++) {
    #pragma unroll
    for (int j = 0; j < 8; j++) {
      int n = nBase + j * 16 + l15;
      float bv = bias ? bias[n] : 0.f;
      #pragma unroll
      for (int r = 0; r < 4; r++) {
        long row = mBase + wv * 32 + i * 16 + l4 * 4 + r;
        float vv = acc[i][j][r] + bv;
        if (RELU) vv = fmaxf(vv, 0.f);
        if (RES)  vv += resid[row * N + n];
        if (OBF) ((u16*)outp)[row * N + n] = f2bf(vv);
        else     ((float*)outp)[row * N + n] = vv;
      }
    }
  }
}

// ------------------------------------------------------------- head GEMM
template<int OBF>
__global__ __launch_bounds__(256) void gemm_head(const u16* __restrict__ A,
    const u16* __restrict__ Wt, const float* __restrict__ bias,
    void* __restrict__ outp, int N, int K)
{
  __shared__ __align__(16) u16 As[4][128][8];
  __shared__ __align__(16) u16 Bs[4][64][8];
  int tid  = threadIdx.x;
  int nt   = blockIdx.x;
  int nBase = nt * 64;
  long mBase = (long)blockIdx.y * 128;
  int lane = tid & 63, wv = tid >> 6;
  int l15 = lane & 15, l4 = lane >> 4;
  int sseg = tid & 3;
  int srow = tid >> 2;
  const u16* a0p = A + (mBase + srow) * K + sseg * 8;
  const u16* a1p = a0p + (long)64 * K;
  bool colOK = (nBase + srow) < N;
  const u16* bp  = Wt + (long)(nBase + srow) * K + sseg * 8;

  f32x4 acc[2][4];
  #pragma unroll
  for (int i = 0; i < 2; i++)
    #pragma unroll
    for (int j = 0; j < 4; j++)
      acc[i][j] = (f32x4){0.f, 0.f, 0.f, 0.f};

  for (int k0 = 0; k0 < K; k0 += 32) {
    uint4 av0 = *(const uint4*)(a0p + k0);
    uint4 av1 = *(const uint4*)(a1p + k0);
    uint4 bv  = colOK ? *(const uint4*)(bp + k0) : make_uint4(0, 0, 0, 0);
    *(uint4*)&As[sseg][srow][0]      = av0;
    *(uint4*)&As[sseg][srow + 64][0] = av1;
    *(uint4*)&Bs[sseg][srow][0]      = bv;
    __syncthreads();
    bf16x8 af[2], bfr[4];
    af[0] = *(const bf16x8*)&As[l4][wv * 32 + l15][0];
    af[1] = *(const bf16x8*)&As[l4][wv * 32 + 16 + l15][0];
    #pragma unroll
    for (int j = 0; j < 4; j++)
      bfr[j] = *(const bf16x8*)&Bs[l4][j * 16 + l15][0];
    #pragma unroll
    for (int i = 0; i < 2; i++)
      #pragma unroll
      for (int j = 0; j < 4; j++)
        acc[i][j] = __builtin_amdgcn_mfma_f32_16x16x32_bf16(
            af[i], bfr[j], acc[i][j], 0, 0, 0);
    __syncthreads();
  }

  #pragma unroll
  for (int i = 0; i < 2; i++) {
    #pragma unroll
    for (int j = 0; j < 4; j++) {
      int n = nBase + j * 16 + l15;
      if (n < N) {
        #pragma unroll
        for (int r = 0; r < 4; r++) {
          long row = mBase + wv * 32 + i * 16 + l4 * 4 + r;
          float vv = acc[i][j][r];
          if (bias) vv += bias[n];
          if (OBF) ((u16*)outp)[row * N + n] = f2bf(vv);
          else     ((float*)outp)[row * N + n] = vv;
        }
      }
    }
  }
}

// ---------------------------------------------------------------- attention
// MFMA flash-style (whole sequence fits): one block per (b, head).
// qkv bf16 [BTc][1152] (q|k|v sections, head-major); ao bf16 [BTc][384].
// Wave w owns query rows 16w..16w+15. S = QK^T via mfma (A=q, B=k rows);
// softmax in C-layout regs; P -> LDS bf16; O = P V via mfma (B=vT rows).
__global__ __launch_bounds__(256) void attn_k(const u16* __restrict__ qkv,
    u16* __restrict__ ao)
{
  __shared__ __align__(16) u16 qs[64][72];
  __shared__ __align__(16) u16 ks[64][72];
  __shared__ __align__(16) u16 vT[64][72];
  __shared__ __align__(16) u16 ps[64][72];
  int tid = threadIdx.x;
  int bb = blockIdx.x / H_;
  int hh = blockIdx.x % H_;
  const u16* base = qkv + ((long)bb * T_) * 1152 + hh * HS_;

  // zero vT so padded k-columns (j=60..63) contribute exact zeros in PV
  for (int i = tid; i < 576; i += 256)
    ((uint4*)vT)[i] = make_uint4(0, 0, 0, 0);
  __syncthreads();

  for (int i = tid; i < 480; i += 256) {        // 60 rows x 8 d-segments
    int t = i >> 3, d0 = (i & 7) << 3;
    const u16* rp = base + (long)t * 1152;
    *(uint4*)&qs[t][d0] = *(const uint4*)(rp + d0);
    *(uint4*)&ks[t][d0] = *(const uint4*)(rp + 384 + d0);
    uint4 rv = *(const uint4*)(rp + 768 + d0);
    u16 vv[8] = {(u16)(rv.x & 0xffffu), (u16)(rv.x >> 16),
                 (u16)(rv.y & 0xffffu), (u16)(rv.y >> 16),
                 (u16)(rv.z & 0xffffu), (u16)(rv.z >> 16),
                 (u16)(rv.w & 0xffffu), (u16)(rv.w >> 16)};
    #pragma unroll
    for (int m = 0; m < 8; m++) vT[d0 + m][t] = vv[m];
  }
  __syncthreads();

  int lane = tid & 63, wv = tid >> 6;
  int l15 = lane & 15, quad = lane >> 4;

  // ---- S = Q K^T for rows 16w..16w+15 (4 col-tiles) ----
  bf16x8 aq0 = *(const bf16x8*)&qs[wv * 16 + l15][quad * 8];
  bf16x8 aq1 = *(const bf16x8*)&qs[wv * 16 + l15][32 + quad * 8];
  f32x4 s[4];
  #pragma unroll
  for (int jt = 0; jt < 4; jt++) {
    bf16x8 b0 = *(const bf16x8*)&ks[jt * 16 + l15][quad * 8];
    bf16x8 b1 = *(const bf16x8*)&ks[jt * 16 + l15][32 + quad * 8];
    f32x4 a2 = (f32x4){0.f, 0.f, 0.f, 0.f};
    a2 = __builtin_amdgcn_mfma_f32_16x16x32_bf16(aq0, b0, a2, 0, 0, 0);
    a2 = __builtin_amdgcn_mfma_f32_16x16x32_bf16(aq1, b1, a2, 0, 0, 0);
    s[jt] = a2;
  }

  // ---- causal softmax per row (C-layout: row = 16w+quad*4+r, col = jt*16+l15)
  int rbase = wv * 16 + quad * 4;
  #pragma unroll
  for (int r = 0; r < 4; r++) {
    int row = rbase + r;
    float v0[4];
    #pragma unroll
    for (int jt = 0; jt < 4; jt++) {
      int col = jt * 16 + l15;
      float sv = s[jt][r] * 0.125f;
      v0[jt] = (col <= row) ? sv : -1e30f;
    }
    float m = fmaxf(fmaxf(v0[0], v0[1]), fmaxf(v0[2], v0[3]));
    #pragma unroll
    for (int off = 1; off < 16; off <<= 1) m = fmaxf(m, __shfl_xor(m, off, 64));
    float sum = 0.f;
    #pragma unroll
    for (int jt = 0; jt < 4; jt++) { v0[jt] = __expf(v0[jt] - m); sum += v0[jt]; }
    #pragma unroll
    for (int off = 1; off < 16; off <<= 1) sum += __shfl_xor(sum, off, 64);
    float inv = 1.f / sum;
    #pragma unroll
    for (int jt = 0; jt < 4; jt++)
      ps[row][jt * 16 + l15] = f2bf(v0[jt] * inv);
  }
  __syncthreads();

  // ---- O = P V for rows 16w..16w+15 ----
  bf16x8 ap0 = *(const bf16x8*)&ps[wv * 16 + l15][quad * 8];
  bf16x8 ap1 = *(const bf16x8*)&ps[wv * 16 + l15][32 + quad * 8];
  long obase = ((long)bb * T_) * C_ + hh * HS_;
  #pragma unroll
  for (int dt = 0; dt < 4; dt++) {
    bf16x8 b0 = *(const bf16x8*)&vT[dt * 16 + l15][quad * 8];
    bf16x8 b1 = *(const bf16x8*)&vT[dt * 16 + l15][32 + quad * 8];
    f32x4 a2 = (f32x4){0.f, 0.f, 0.f, 0.f};
    a2 = __builtin_amdgcn_mfma_f32_16x16x32_bf16(ap0, b0, a2, 0, 0, 0);
    a2 = __builtin_amdgcn_mfma_f32_16x16x32_bf16(ap1, b1, a2, 0, 0, 0);
    #pragma unroll
    for (int r = 0; r < 4; r++) {
      int row = rbase + r;
      if (row < T_)
        ao[obase + (long)row * C_ + dt * 16 + l15] = f2bf(a2[r]);
    }
  }
}

// ---------------------------------------------------------------- launch
extern "C" void kernel_launch(void* const* d_in, const int* in_sizes, int n_in,
                              void* d_out, int out_size, void* d_ws, size_t ws_size,
                              hipStream_t stream)
{
  const int*   ctx  = (const int*)  d_in[0];
  const float* tok  = (const float*)d_in[1];
  const float* pos  = (const float*)d_in[2];
  const float* wq   = (const float*)d_in[3];
  const float* wk   = (const float*)d_in[4];
  const float* wv   = (const float*)d_in[5];
  const float* wo   = (const float*)d_in[6];
  const float* bo   = (const float*)d_in[7];
  const float* ln1g = (const float*)d_in[8];
  const float* ln1b = (const float*)d_in[9];
  const float* ln2g = (const float*)d_in[10];
  const float* ln2b = (const float*)d_in[11];
  const float* w1   = (const float*)d_in[12];
  const float* b1   = (const float*)d_in[13];
  const float* w2   = (const float*)d_in[14];
  const float* b2   = (const float*)d_in[15];
  const float* lnfg = (const float*)d_in[16];
  const float* lnfb = (const float*)d_in[17];
  const float* lmw  = (const float*)d_in[18];
  const float* lmb  = (const float*)d_in[19];
  float* out = (float*)d_out;

  const long nQKV = (long)L_ * H_ * C_ * HS_;
  const long nWO  = (long)L_ * C_ * C_;
  const long nW1  = (long)L_ * C_ * FF_;
  const long nLM  = (long)C_ * V_;
  u16* wqkvT = (u16*)d_ws;                       // [L][1152][384]
  u16* woT = wqkvT + 3 * nQKV;
  u16* w1T = woT + nWO;
  u16* w2T = w1T + nW1;
  u16* lmT = w2T + nW1;
  const size_t wbytes = (size_t)(nQKV * 3 + nWO + nW1 * 2 + nLM) * 2;

  int chunkB = 32;
  {
    const int cand[] = {2048, 1024, 512, 256, 128, 64, 32};
    for (int i = 0; i < 7; i++) {
      size_t U = (size_t)cand[i] * T_ * C_ * 2;
      if (wbytes + 7 * U <= ws_size) { chunkB = cand[i]; break; }
    }
  }
  const long BTc = (long)chunkB * T_;
  char* wsb = (char*)d_ws + wbytes;
  const size_t U = (size_t)BTc * C_ * 2;
  float* x    = (float*)wsb;             // 2U
  u16*   h    = (u16*)(wsb + 2 * U);     // 1U
  char*  reg  = wsb + 3 * U;             // 4U: qkv(3U) + ab(1U); fb aliases
  u16* qkvb = (u16*)reg;
  u16* ab   = (u16*)(reg + 3 * U);
  u16* fb   = (u16*)reg;                 // alias: qkv/ab dead before MLP

  {
    dim3 tb(32, 8);
    const long sL = 1152L * 384, sH = 64L * 384, sec = 384L * 384;
    tconv_k<<<dim3(2, 12, L_ * H_), tb, 0, stream>>>(wq, wqkvT,
        C_, HS_, (long)C_ * HS_, H_, sL, sH);
    tconv_k<<<dim3(2, 12, L_ * H_), tb, 0, stream>>>(wk, wqkvT + sec,
        C_, HS_, (long)C_ * HS_, H_, sL, sH);
    tconv_k<<<dim3(2, 12, L_ * H_), tb, 0, stream>>>(wv, wqkvT + 2 * sec,
        C_, HS_, (long)C_ * HS_, H_, sL, sH);
    tconv_k<<<dim3(12, 12, L_), tb, 0, stream>>>(wo, woT,
        C_, C_, (long)C_ * C_, 1, (long)C_ * C_, 0);
    tconv_k<<<dim3(48, 12, L_), tb, 0, stream>>>(w1, w1T,
        C_, FF_, (long)C_ * FF_, 1, (long)C_ * FF_, 0);
    tconv_k<<<dim3(12, 48, L_), tb, 0, stream>>>(w2, w2T,
        FF_, C_, (long)FF_ * C_, 1, (long)FF_ * C_, 0);
    tconv_k<<<dim3(3, 12, 1), tb, 0, stream>>>(lmw, lmT,
        C_, V_, (long)C_ * V_, 1, 0, 0);
  }

  const long qkvL = 1152L * 384;
  const long woL  = (long)C_ * C_;
  const long w1L  = (long)C_ * FF_;
  dim3 blk(256);
  dim3 gEmb((u32)(BTc * C_ / 4 / 256));
  dim3 gLN((u32)(BTc / 4));
  u32 mT = (u32)(BTc / 128);
  dim3 gQKV(9, mT), gWO(3, mT), gW1(12, mT), gW2(3, mT);
  dim3 gHd(2, mT);
  dim3 gAt((u32)(chunkB * H_));

  for (int c0 = 0; c0 < B_; c0 += chunkB) {
    const long tok0 = (long)c0 * T_;
    const int* ctxc = ctx + tok0;
    float* outc = out + tok0 * V_;

    embed_k<<<gEmb, blk, 0, stream>>>(ctxc, tok, pos, x);

    for (int l = 0; l < L_; l++) {
      ln_k<<<gLN, blk, 0, stream>>>(x, ln1g + l * C_, ln1b + l * C_, h);
      gemm128<0,0,1><<<gQKV, blk, 0, stream>>>(h, wqkvT + l * qkvL,
          nullptr, nullptr, qkvb, 1152, C_);
      attn_k<<<gAt, blk, 0, stream>>>(qkvb, ab);
      gemm128<0,1,0><<<gWO, blk, 0, stream>>>(ab, woT + l * woL,
          bo + l * C_, x, x, C_, C_);
      ln_k<<<gLN, blk, 0, stream>>>(x, ln2g + l * C_, ln2b + l * C_, h);
      gemm128<1,0,1><<<gW1, blk, 0, stream>>>(h, w1T + l * w1L,
          b1 + l * FF_, nullptr, fb, FF_, C_);
      gemm128<0,1,0><<<gW2, blk, 0, stream>>>(fb, w2T + l * w1L,
          b2 + l * C_, x, x, C_, FF_);
    }

    ln_k<<<gLN, blk, 0, stream>>>(x, lnfg, lnfb, h);
    gemm_head<0><<<gHd, blk, 0, stream>>>(h, lmT, lmb, outc, V_, C_);
  }
}